// Round 9
// baseline (38152.649 us; speedup 1.0000x reference)
//
#include <hip/hip_runtime.h>

// ============================================================================
// Bidirectional 2-layer LSTM, T=1024 B=64 I=H=512, fp32 in/out.
// Round 9: STREAM-ORDERED PHASES. Per layer: 16 phases x (k_xg GEMM launch ->
// cooperative k_scan launch of 64 steps). xg sync = kernel boundaries (no
// producer blocks, no ring, no ready flags, no backpressure -- the r7/r8
// suspect cluster is deleted). k_xg is r2's PROVEN k_step x-part verbatim
// (same pack layout, same Abase addressing, bias in fp32) + bf16 store.
// k_scan: gate-split 8 blocks/dir, W_hh register-resident (Wreg, r2-layout),
// h all-gather via r6-PROVEN parts: scalar sc1 publish, relaxed flag after
// __syncthreads, sc1 staging reads. LDS h tile in m97 fragment-contiguous
// order (linear writes, 64-consecutive-16B reads: conflict-free both ways).
// c-state persisted in ws across phases.
// ============================================================================

using bfrag = __attribute__((ext_vector_type(8))) short;   // 8 x bf16 bits
using facc  = __attribute__((ext_vector_type(4))) float;   // 4 x f32 acc
typedef unsigned long long u64;

__device__ __forceinline__ unsigned short f2bf(float f) {
  union { float f; unsigned u; } v; v.f = f;
  unsigned r = v.u + 0x7fffu + ((v.u >> 16) & 1u);   // RNE
  return (unsigned short)(r >> 16);
}
__device__ __forceinline__ float bf2f(unsigned short u) {
  union { unsigned u; float f; } v; v.u = ((unsigned)u) << 16; return v.f;
}
__device__ __forceinline__ float sigm(float x)  { return 1.f / (1.f + __expf(-x)); }
__device__ __forceinline__ float tanhf_(float x){ return 1.f - 2.f / (__expf(2.f * x) + 1.f); }

__device__ __forceinline__ facc mfma_bf16(bfrag a, bfrag b, facc c) {
  asm("v_mfma_f32_16x16x32_bf16 %0, %1, %2, %0" : "+v"(c) : "v"(a), "v"(b));
  return c;
}
__device__ __forceinline__ u64 pack4bf(facc a) {
  return (u64)f2bf(a[0]) | ((u64)f2bf(a[1]) << 16)
       | ((u64)f2bf(a[2]) << 32) | ((u64)f2bf(a[3]) << 48);
}
__device__ __forceinline__ u64 ald(const u64* p) {
  return __hip_atomic_load(p, __ATOMIC_RELAXED, __HIP_MEMORY_SCOPE_AGENT);
}
__device__ __forceinline__ unsigned ald32(const unsigned* p) {
  return __hip_atomic_load(p, __ATOMIC_RELAXED, __HIP_MEMORY_SCOPE_AGENT);
}
__device__ __forceinline__ void ast16(unsigned short* p, unsigned short v) {
  __hip_atomic_store(p, v, __ATOMIC_RELAXED, __HIP_MEMORY_SCOPE_AGENT);
}
__device__ __forceinline__ void ast32(unsigned* p, unsigned v) {
  __hip_atomic_store(p, v, __ATOMIC_RELAXED, __HIP_MEMORY_SCOPE_AGENT);
}

// ---------------------------------------------------------------- prep ----
__global__ __launch_bounds__(256) void k_cvt_x(const float* __restrict__ x,
                                               unsigned short* __restrict__ xb) {
  int i = blockIdx.x * 256 + threadIdx.x;          // 8,388,608 threads x 4 elems
  float4 v = reinterpret_cast<const float4*>(x)[i];
  ushort4 o;
  o.x = f2bf(v.x); o.y = f2bf(v.y); o.z = f2bf(v.z); o.w = f2bf(v.w);
  reinterpret_cast<ushort4*>(xb)[i] = o;
}

__global__ __launch_bounds__(256) void k_init(const float* __restrict__ h0,
                                              const float* __restrict__ c0,
                                              unsigned short* __restrict__ h0b,
                                              float* __restrict__ cbuf,
                                              unsigned* __restrict__ hxf) {
  int i = blockIdx.x * 256 + threadIdx.x;          // 32768 = 64*512
  h0b[i] = f2bf(h0[i]);
  float c = c0[i];
  cbuf[i] = c; cbuf[32768 + i] = c; cbuf[65536 + i] = c; cbuf[98304 + i] = c;
  if (i < 128) hxf[i] = 0;                         // [2L][2dir][16-pad: 8 used]
}

// r2-PROVEN pack: packed row R = g*16 + q*4 + gate (hcol = g*4+q, gate order
// i,f,g,o); PW row-major [2048][K], row = [W_ih | W_hh]. PB[R] = bias[srow].
template <int KX>
__global__ __launch_bounds__(256) void k_pack(const float* __restrict__ Wih,
                                              const float* __restrict__ Whh,
                                              const float* __restrict__ bias,
                                              unsigned short* __restrict__ PW,
                                              float* __restrict__ PB) {
  constexpr int K = KX + 512;
  int tid = blockIdx.x * 256 + threadIdx.x;        // exact grid: 2048*K threads
  int R = tid / K;
  int k = tid - R * K;
  int g = R >> 4, r = R & 15;
  int q = r >> 2, gate = r & 3;
  int srow = gate * 512 + (g * 4 + q);
  float v = (k < KX) ? Wih[srow * KX + k] : Whh[srow * 512 + (k - KX)];
  PW[tid] = f2bf(v);
  if (k == 0) PB[R] = bias[srow];
}

// ------------------------------------------------------------------ xg ----
// grid 256 = [dir = bid>>7][hg = bid&127] x 256 thr (4 waves = 4 batch tiles).
// Computes xg (= W_ih x + b) bf16 for 64 timesteps of phase ph, both dirs.
// Structure is r2's k_step x-part verbatim.
template <int LAYER>
__global__ __launch_bounds__(256) void k_xg(
    int ph,
    const unsigned short* __restrict__ xin,  // L0: xb [T][64][512]; L1: y0 [T][64][1024]
    unsigned short* __restrict__ xgq,        // [2 dir][64 sl][64 b][2048] bf16
    const unsigned short* __restrict__ PWf, const unsigned short* __restrict__ PWb,
    const float* __restrict__ PBf, const float* __restrict__ PBb) {
  constexpr int KX = (LAYER == 0) ? 512 : 1024;
  constexpr int K  = KX + 512;
  const int bid = blockIdx.x;
  const int dir = bid >> 7, hg = bid & 127;
  const int wv = threadIdx.x >> 6, lane = threadIdx.x & 63;
  const int lr = lane & 15, lq = lane >> 4;
  const int b = wv * 16 + lr;
  const unsigned short* pw = dir ? PWb : PWf;
  const float* pb          = dir ? PBb : PBf;
  const unsigned short* Abase = pw + (size_t)(hg * 16 + lr) * K + lq * 8;
  const float4 bias = *reinterpret_cast<const float4*>(pb + hg * 16 + lq * 4);

  for (int sl = 0; sl < 64; ++sl) {
    const int s = ph * 64 + sl;
    const int t = dir ? (1023 - s) : s;
    const unsigned short* xrow = xin + ((size_t)t * 64 + b) * KX + lq * 8;
    facc acc = {0.f, 0.f, 0.f, 0.f};
    asm volatile("s_nop 3" : "+v"(acc));            // VALU init -> MFMA srcC
#pragma unroll 8
    for (int kk = 0; kk < KX / 32; ++kk) {
      bfrag a  = *reinterpret_cast<const bfrag*>(Abase + kk * 32);
      bfrag xf = *reinterpret_cast<const bfrag*>(xrow + kk * 32);
      acc = mfma_bf16(a, xf, acc);
    }
    asm volatile("s_nop 7\n\ts_nop 7" : "+v"(acc)); // MFMA D -> VALU
    acc[0] += bias.x; acc[1] += bias.y; acc[2] += bias.z; acc[3] += bias.w;
    // lane's acc = packed rows hg*16 + lq*4 + {0..3} for batch b
    u64* dst = reinterpret_cast<u64*>(
        xgq + (((size_t)dir * 64 + sl) * 64 + b) * 2048 + hg * 16 + lq * 4);
    *dst = pack4bf(acc);
  }
}

// ---------------------------------------------------------------- scan ----
// cooperative, grid 16 = [dir = bid&1][g = bid>>1] x 512 thr (8 waves).
// Wave w owns rowtiles g*16 + w*2 + {0,1} (W_hh slice in Wreg registers).
// LDS h tile: fragment-contiguous [kt 16][bt 4][lq 4][lr 16][8]us = 64KB.
template <int LAYER>
__global__ __launch_bounds__(512, 2) void k_scan(
    int ph,
    const unsigned short* __restrict__ xgq,  // [2][64][64][2048] bf16
    unsigned short* __restrict__ y0,         // L0 out [T][64][1024] bf16
    float* __restrict__ dout,                // y1 | hn | cn
    const unsigned short* __restrict__ h0b,  // [64][512] bf16
    float* __restrict__ cbuf,                // [4][64][512] f32 (slot L*2+dir)
    unsigned short* __restrict__ hx,         // [2dir x 2par][64][512] bf16
    const unsigned short* __restrict__ PWf, const unsigned short* __restrict__ PWb,
    unsigned* __restrict__ hxf) {            // [2L][2dir][16-pad]
  constexpr int KX = (LAYER == 0) ? 512 : 1024;
  constexpr int K  = KX + 512;
  extern __shared__ unsigned short Hlds[];   // 32768 us = 64KB

  const int bid = blockIdx.x;
  const int dir = bid & 1, g = bid >> 1;
  const int tid = threadIdx.x;
  const int w = tid >> 6, lane = tid & 63;
  const int lr = lane & 15, lq = lane >> 4;
  const unsigned short* pw = dir ? PWb : PWf;
  unsigned* hxfd = hxf + (LAYER * 2 + dir) * 16;

  // W_hh slice -> registers (r2-layout: row-major [2048][K], hh at +KX)
  bfrag Wreg[32];
#pragma unroll
  for (int rtl = 0; rtl < 2; ++rtl)
#pragma unroll
    for (int kt = 0; kt < 16; ++kt)
      Wreg[rtl * 16 + kt] = *reinterpret_cast<const bfrag*>(
          pw + (size_t)((g * 16 + w * 2 + rtl) * 16 + lr) * K + KX + kt * 32 + lq * 8);

  const int slot = LAYER * 2 + dir;
  float cst[2][4];
#pragma unroll
  for (int rtl = 0; rtl < 2; ++rtl)
#pragma unroll
    for (int bt = 0; bt < 4; ++bt)
      cst[rtl][bt] = cbuf[((size_t)slot * 64 + bt * 16 + lr) * 512
                          + g * 64 + w * 8 + rtl * 4 + lq];

  for (int sl = 0; sl < 64; ++sl) {
    const int s = ph * 64 + sl;
    const int t = dir ? (1023 - s) : s;

    // xg for this step (plain loads; xgq fixed for the whole launch)
    u64 xv[2][4];
#pragma unroll
    for (int rtl = 0; rtl < 2; ++rtl)
#pragma unroll
      for (int bt = 0; bt < 4; ++bt)
        xv[rtl][bt] = *reinterpret_cast<const u64*>(
            xgq + (((size_t)dir * 64 + sl) * 64 + bt * 16 + lr) * 2048
                + g * 256 + w * 32 + rtl * 16 + lq * 4);

    // wait: all 8 gate-slice blocks of this dir published h(s-1)
    if (s > 0) {
      while (ald32(&hxfd[lane & 7]) < (unsigned)s) __builtin_amdgcn_s_sleep(8);
    }
    __syncthreads();

    // stage h(s-1) -> LDS, fragment-contiguous; writes are LINEAR (slot*8)
    const unsigned short* hsrc = (s == 0)
        ? h0b : hx + (size_t)(dir * 2 + ((s - 1) & 1)) * 32768;
#pragma unroll
    for (int it = 0; it < 8; ++it) {
      const int sidx = it * 512 + tid;          // 4096 slots of 8us
      const int C = sidx >> 4, lrs = sidx & 15;
      const int kts = C >> 4, bts = (C >> 2) & 3, lqs = C & 3;
      const int src = (bts * 16 + lrs) * 512 + kts * 32 + lqs * 8;
      u64 d0 = ald(reinterpret_cast<const u64*>(hsrc + src));
      u64 d1 = ald(reinterpret_cast<const u64*>(hsrc + src + 4));
      u64* dp = reinterpret_cast<u64*>(Hlds + sidx * 8);
      dp[0] = d0; dp[1] = d1;
    }
    __syncthreads();

    // MFMA: acc = xg + Whh_slice * h(s-1)
    facc acc[2][4];
#pragma unroll
    for (int rtl = 0; rtl < 2; ++rtl)
#pragma unroll
      for (int bt = 0; bt < 4; ++bt) {
        acc[rtl][bt][0] = bf2f((unsigned short)(xv[rtl][bt] & 0xffff));
        acc[rtl][bt][1] = bf2f((unsigned short)((xv[rtl][bt] >> 16) & 0xffff));
        acc[rtl][bt][2] = bf2f((unsigned short)((xv[rtl][bt] >> 32) & 0xffff));
        acc[rtl][bt][3] = bf2f((unsigned short)((xv[rtl][bt] >> 48) & 0xffff));
      }
    asm volatile("s_nop 3"
                 : "+v"(acc[0][0]), "+v"(acc[0][1]), "+v"(acc[0][2]), "+v"(acc[0][3]),
                   "+v"(acc[1][0]), "+v"(acc[1][1]), "+v"(acc[1][2]), "+v"(acc[1][3]));
#pragma unroll
    for (int kt = 0; kt < 16; ++kt) {
      bfrag Bv[4];
#pragma unroll
      for (int bt = 0; bt < 4; ++bt)   // 64 consecutive 16B chunks per (kt,bt)
        Bv[bt] = *reinterpret_cast<const bfrag*>(
            Hlds + (((kt * 4 + bt) * 4 + lq) * 16 + lr) * 8);
#pragma unroll
      for (int rtl = 0; rtl < 2; ++rtl)
#pragma unroll
        for (int bt = 0; bt < 4; ++bt)
          acc[rtl][bt] = mfma_bf16(Wreg[rtl * 16 + kt], Bv[bt], acc[rtl][bt]);
    }
    asm volatile("s_nop 7\n\ts_nop 7"
                 : "+v"(acc[0][0]), "+v"(acc[0][1]), "+v"(acc[0][2]), "+v"(acc[0][3]),
                   "+v"(acc[1][0]), "+v"(acc[1][1]), "+v"(acc[1][2]), "+v"(acc[1][3]));

    // gates, state, publish (r6-proven scalar sc1 stores), outputs
#pragma unroll
    for (int rtl = 0; rtl < 2; ++rtl)
#pragma unroll
      for (int bt = 0; bt < 4; ++bt) {
        float ig = sigm(acc[rtl][bt][0]);
        float fg = sigm(acc[rtl][bt][1]);
        float gv = tanhf_(acc[rtl][bt][2]);
        float og = sigm(acc[rtl][bt][3]);
        cst[rtl][bt] = fg * cst[rtl][bt] + ig * gv;
        const float h2 = og * tanhf_(cst[rtl][bt]);
        const int b = bt * 16 + lr;
        const int hcol = g * 64 + w * 8 + rtl * 4 + lq;
        ast16(&hx[(size_t)(dir * 2 + (s & 1)) * 32768 + (size_t)b * 512 + hcol],
              f2bf(h2));
        const size_t orow = ((size_t)t * 64 + b) * 1024 + dir * 512 + hcol;
        if constexpr (LAYER == 0) y0[orow] = f2bf(h2);
        else                      dout[orow] = h2;
        if (s == 1023) {
          const size_t oh = ((size_t)LAYER * 64 + b) * 1024 + dir * 512 + hcol;
          dout[67108864 + oh] = h2;
          dout[67239936 + oh] = cst[rtl][bt];
        }
      }
    __syncthreads();                             // drains all waves' hx stores
    if (tid == 0) ast32(&hxfd[g], (unsigned)(s + 1));
  }

  // persist c-state for the next phase launch
#pragma unroll
  for (int rtl = 0; rtl < 2; ++rtl)
#pragma unroll
    for (int bt = 0; bt < 4; ++bt)
      cbuf[((size_t)slot * 64 + bt * 16 + lr) * 512
           + g * 64 + w * 8 + rtl * 4 + lq] = cst[rtl][bt];
}

// -------------------------------------------------------------- launch ----
extern "C" void kernel_launch(void* const* d_in, const int* in_sizes, int n_in,
                              void* d_out, int out_size, void* d_ws, size_t ws_size,
                              hipStream_t stream) {
  (void)in_sizes; (void)n_in; (void)out_size; (void)ws_size;
  const float* x  = (const float*)d_in[0];
  const float* h0 = (const float*)d_in[1];
  const float* c0 = (const float*)d_in[2];
  const float* W[12];
  for (int i = 0; i < 12; ++i) W[i] = (const float*)d_in[3 + i];
  // W: Wih0f,Whh0f,b0f, Wih0b,Whh0b,b0b, Wih1f,Whh1f,b1f, Wih1b,Whh1b,b1b

  // ws layout (bytes), total ~245 MB (< 256 MiB)
  char* ws = (char*)d_ws;
  unsigned short* xb   = (unsigned short*)(ws + 0ull);           //  64 MB
  unsigned short* y0   = (unsigned short*)(ws + 67108864ull);    // 128 MB
  unsigned short* xgq  = (unsigned short*)(ws + 201326592ull);   //  32 MB
  unsigned short* PW0F = (unsigned short*)(ws + 234881024ull);   //   4 MB
  unsigned short* PW0B = (unsigned short*)(ws + 239075328ull);   //   4 MB
  unsigned short* PW1F = (unsigned short*)(ws + 243269632ull);   //   6 MB
  unsigned short* PW1B = (unsigned short*)(ws + 249561088ull);   //   6 MB
  float*          PB   = (float*)(ws + 255852544ull);            //  32 KB [4][2048]
  unsigned short* h0b  = (unsigned short*)(ws + 255885312ull);   //  64 KB
  float*          cbuf = (float*)(ws + 255950848ull);            // 512 KB [4][64][512]
  unsigned short* hx   = (unsigned short*)(ws + 256475136ull);   // 256 KB
  unsigned*       hxf  = (unsigned*)(ws + 256737280ull);         // 512 B
  float* dout = (float*)d_out;

  k_cvt_x<<<32768, 256, 0, stream>>>(x, xb);
  k_init<<<128, 256, 0, stream>>>(h0, c0, h0b, cbuf, hxf);
  k_pack<512> <<<8192, 256, 0, stream>>>(W[0], W[1],  W[2],  PW0F, PB + 0);
  k_pack<512> <<<8192, 256, 0, stream>>>(W[3], W[4],  W[5],  PW0B, PB + 2048);
  k_pack<1024><<<12288, 256, 0, stream>>>(W[6], W[7],  W[8],  PW1F, PB + 4096);
  k_pack<1024><<<12288, 256, 0, stream>>>(W[9], W[10], W[11], PW1B, PB + 6144);

  (void)hipFuncSetAttribute((const void*)(&k_scan<0>),
                            hipFuncAttributeMaxDynamicSharedMemorySize, 65536);
  (void)hipFuncSetAttribute((const void*)(&k_scan<1>),
                            hipFuncAttributeMaxDynamicSharedMemorySize, 65536);

  unsigned short *xgqp = xgq, *y0p = y0, *h0bp = h0b, *hxp = hx;
  float *cbufp = cbuf;
  unsigned* hxfp = hxf;
  const unsigned short *pw0f = PW0F, *pw0b = PW0B, *pw1f = PW1F, *pw1b = PW1B;
  float* doutp = dout;

  for (int ph = 0; ph < 16; ++ph) {
    k_xg<0><<<256, 256, 0, stream>>>(ph, xb, xgq, PW0F, PW0B, PB + 0, PB + 2048);
    int phv = ph;
    void* as[] = {(void*)&phv, (void*)&xgqp, (void*)&y0p, (void*)&doutp,
                  (void*)&h0bp, (void*)&cbufp, (void*)&hxp,
                  (void*)&pw0f, (void*)&pw0b, (void*)&hxfp};
    (void)hipLaunchCooperativeKernel((const void*)(&k_scan<0>), dim3(16), dim3(512),
                                     as, 65536, stream);
  }
  for (int ph = 0; ph < 16; ++ph) {
    k_xg<1><<<256, 256, 0, stream>>>(ph, y0, xgq, PW1F, PW1B, PB + 4096, PB + 6144);
    int phv = ph;
    void* as[] = {(void*)&phv, (void*)&xgqp, (void*)&y0p, (void*)&doutp,
                  (void*)&h0bp, (void*)&cbufp, (void*)&hxp,
                  (void*)&pw1f, (void*)&pw1b, (void*)&hxfp};
    (void)hipLaunchCooperativeKernel((const void*)(&k_scan<1>), dim3(16), dim3(512),
                                     as, 65536, stream);
  }
}

// Round 11
// 29751.566 us; speedup vs baseline: 1.2824x; 1.2824x over previous
//
#include <hip/hip_runtime.h>

// ============================================================================
// Bidirectional 2-layer LSTM, T=1024 B=64 I=H=512, fp32 in/out.
// Round 11 = r9 (PASSED) with the EXCHANGE DATA PATH rebuilt:
//  - publish: LDS repack -> coalesced 16B sc1 stores (was 2-byte sc1 scatter)
//  - consume: CACHED loads from full-T rings (L0: y0 bf16, L1: dout fp32 +
//    in-thread cvt). Every staged address is read exactly once -> no stale
//    lines; sc1 publishes land in IF$ where consumer L2 misses fetch.
//  - k_xg: loop-invariant A-fragments hoisted to registers.
// Sync protocol = r9 VERBATIM (agent-scope atomics, poll + __syncthreads).
// No XCD tricks, no plain-store flags, no sc0 asm (r10 deadlock lesson).
// ============================================================================

using bfrag = __attribute__((ext_vector_type(8))) short;   // 8 x bf16 bits
using facc  = __attribute__((ext_vector_type(4))) float;   // 4 x f32 acc
typedef unsigned long long u64;

__device__ __forceinline__ unsigned short f2bf(float f) {
  union { float f; unsigned u; } v; v.f = f;
  unsigned r = v.u + 0x7fffu + ((v.u >> 16) & 1u);   // RNE
  return (unsigned short)(r >> 16);
}
__device__ __forceinline__ float bf2f(unsigned short u) {
  union { unsigned u; float f; } v; v.u = ((unsigned)u) << 16; return v.f;
}
__device__ __forceinline__ float sigm(float x)  { return 1.f / (1.f + __expf(-x)); }
__device__ __forceinline__ float tanhf_(float x){ return 1.f - 2.f / (__expf(2.f * x) + 1.f); }

__device__ __forceinline__ facc mfma_bf16(bfrag a, bfrag b, facc c) {
  asm("v_mfma_f32_16x16x32_bf16 %0, %1, %2, %0" : "+v"(c) : "v"(a), "v"(b));
  return c;
}
__device__ __forceinline__ u64 pack4bf(facc a) {
  return (u64)f2bf(a[0]) | ((u64)f2bf(a[1]) << 16)
       | ((u64)f2bf(a[2]) << 32) | ((u64)f2bf(a[3]) << 48);
}
__device__ __forceinline__ unsigned ald32(const unsigned* p) {
  return __hip_atomic_load(p, __ATOMIC_RELAXED, __HIP_MEMORY_SCOPE_AGENT);
}
__device__ __forceinline__ void ast(u64* p, u64 v) {
  __hip_atomic_store(p, v, __ATOMIC_RELAXED, __HIP_MEMORY_SCOPE_AGENT);
}
__device__ __forceinline__ void ast32(unsigned* p, unsigned v) {
  __hip_atomic_store(p, v, __ATOMIC_RELAXED, __HIP_MEMORY_SCOPE_AGENT);
}

// ---------------------------------------------------------------- prep ----
__global__ __launch_bounds__(256) void k_cvt_x(const float* __restrict__ x,
                                               unsigned short* __restrict__ xb) {
  int i = blockIdx.x * 256 + threadIdx.x;          // 8,388,608 threads x 4 elems
  float4 v = reinterpret_cast<const float4*>(x)[i];
  ushort4 o;
  o.x = f2bf(v.x); o.y = f2bf(v.y); o.z = f2bf(v.z); o.w = f2bf(v.w);
  reinterpret_cast<ushort4*>(xb)[i] = o;
}

__global__ __launch_bounds__(256) void k_init(const float* __restrict__ h0,
                                              const float* __restrict__ c0,
                                              unsigned short* __restrict__ h0b,
                                              float* __restrict__ cbuf,
                                              unsigned* __restrict__ hxf) {
  int i = blockIdx.x * 256 + threadIdx.x;          // 32768 = 64*512
  h0b[i] = f2bf(h0[i]);
  float c = c0[i];
  cbuf[i] = c; cbuf[32768 + i] = c; cbuf[65536 + i] = c; cbuf[98304 + i] = c;
  if (i < 128) hxf[i] = 0;                         // [2L][2dir][16-pad: 8 used]
}

// r2-PROVEN pack: packed row R = g*16 + q*4 + gate (hcol = g*4+q, gate order
// i,f,g,o); PW row-major [2048][K], row = [W_ih | W_hh]. PB[R] = bias[srow].
template <int KX>
__global__ __launch_bounds__(256) void k_pack(const float* __restrict__ Wih,
                                              const float* __restrict__ Whh,
                                              const float* __restrict__ bias,
                                              unsigned short* __restrict__ PW,
                                              float* __restrict__ PB) {
  constexpr int K = KX + 512;
  int tid = blockIdx.x * 256 + threadIdx.x;        // exact grid: 2048*K threads
  int R = tid / K;
  int k = tid - R * K;
  int g = R >> 4, r = R & 15;
  int q = r >> 2, gate = r & 3;
  int srow = gate * 512 + (g * 4 + q);
  float v = (k < KX) ? Wih[srow * KX + k] : Whh[srow * 512 + (k - KX)];
  PW[tid] = f2bf(v);
  if (k == 0) PB[R] = bias[srow];
}

// ------------------------------------------------------------------ xg ----
// grid 256 = [dir = bid>>7][hg = bid&127] x 256 thr (4 waves = 4 batch tiles).
// r9 structure + A-fragments hoisted to registers (loop-invariant).
template <int LAYER>
__global__ __launch_bounds__(256) void k_xg(
    int ph,
    const unsigned short* __restrict__ xin,  // L0: xb [T][64][512]; L1: y0 [T][64][1024]
    unsigned short* __restrict__ xgq,        // [2 dir][64 sl][64 b][2048] bf16
    const unsigned short* __restrict__ PWf, const unsigned short* __restrict__ PWb,
    const float* __restrict__ PBf, const float* __restrict__ PBb) {
  constexpr int KX = (LAYER == 0) ? 512 : 1024;
  constexpr int K  = KX + 512;
  const int bid = blockIdx.x;
  const int dir = bid >> 7, hg = bid & 127;
  const int wv = threadIdx.x >> 6, lane = threadIdx.x & 63;
  const int lr = lane & 15, lq = lane >> 4;
  const int b = wv * 16 + lr;
  const unsigned short* pw = dir ? PWb : PWf;
  const float* pb          = dir ? PBb : PBf;
  const unsigned short* Abase = pw + (size_t)(hg * 16 + lr) * K + lq * 8;
  const float4 bias = *reinterpret_cast<const float4*>(pb + hg * 16 + lq * 4);

  bfrag Areg[KX / 32];                             // loop-invariant A slice
#pragma unroll
  for (int kk = 0; kk < KX / 32; ++kk)
    Areg[kk] = *reinterpret_cast<const bfrag*>(Abase + kk * 32);

  for (int sl = 0; sl < 64; ++sl) {
    const int s = ph * 64 + sl;
    const int t = dir ? (1023 - s) : s;
    const unsigned short* xrow = xin + ((size_t)t * 64 + b) * KX + lq * 8;
    facc acc = {0.f, 0.f, 0.f, 0.f};
    asm volatile("s_nop 3" : "+v"(acc));            // VALU init -> MFMA srcC
#pragma unroll
    for (int kk = 0; kk < KX / 32; ++kk) {
      bfrag xf = *reinterpret_cast<const bfrag*>(xrow + kk * 32);
      acc = mfma_bf16(Areg[kk], xf, acc);
    }
    asm volatile("s_nop 7\n\ts_nop 7" : "+v"(acc)); // MFMA D -> VALU
    acc[0] += bias.x; acc[1] += bias.y; acc[2] += bias.z; acc[3] += bias.w;
    u64* dst = reinterpret_cast<u64*>(
        xgq + (((size_t)dir * 64 + sl) * 64 + b) * 2048 + hg * 16 + lq * 4);
    *dst = pack4bf(acc);
  }
}

// ---------------------------------------------------------------- scan ----
// cooperative, grid 16 = [dir = bid&1][g = bid>>1] x 512 thr (8 waves).
// Hlds: fragment-contiguous h tile (64KB). hout: 16KB repack buffer.
template <int LAYER>
__global__ __launch_bounds__(512, 2) void k_scan(
    int ph,
    const unsigned short* __restrict__ xgq,  // [2][64][64][2048] bf16
    unsigned short* __restrict__ y0,         // L0 out/exchange [T][64][1024] bf16
    float* __restrict__ dout,                // y1 (L1 exchange) | hn | cn
    const unsigned short* __restrict__ h0b,  // [64][512] bf16
    float* __restrict__ cbuf,                // [4][64][512] f32 (slot L*2+dir)
    const unsigned short* __restrict__ PWf, const unsigned short* __restrict__ PWb,
    unsigned* __restrict__ hxf) {            // [2L][2dir][16-pad]
  constexpr int KX = (LAYER == 0) ? 512 : 1024;
  constexpr int K  = KX + 512;
  extern __shared__ unsigned short Hlds[];   // 64KB + 16KB hout
  unsigned short* hout16 = Hlds + 32768;
  float*          hout32 = reinterpret_cast<float*>(Hlds + 32768);

  const int bid = blockIdx.x;
  const int dir = bid & 1, g = bid >> 1;
  const int tid = threadIdx.x;
  const int w = tid >> 6, lane = tid & 63;
  const int lr = lane & 15, lq = lane >> 4;
  const unsigned short* pw = dir ? PWb : PWf;
  unsigned* hxfd = hxf + (LAYER * 2 + dir) * 16;

  // W_hh slice -> registers (r9)
  bfrag Wreg[32];
#pragma unroll
  for (int rtl = 0; rtl < 2; ++rtl)
#pragma unroll
    for (int kt = 0; kt < 16; ++kt)
      Wreg[rtl * 16 + kt] = *reinterpret_cast<const bfrag*>(
          pw + (size_t)((g * 16 + w * 2 + rtl) * 16 + lr) * K + KX + kt * 32 + lq * 8);

  const int slot = LAYER * 2 + dir;
  float cst[2][4];
#pragma unroll
  for (int rtl = 0; rtl < 2; ++rtl)
#pragma unroll
    for (int bt = 0; bt < 4; ++bt)
      cst[rtl][bt] = cbuf[((size_t)slot * 64 + bt * 16 + lr) * 512
                          + g * 64 + w * 8 + rtl * 4 + lq];

  for (int sl = 0; sl < 64; ++sl) {
    const int s = ph * 64 + sl;
    const int t = dir ? (1023 - s) : s;
    const int tp = dir ? (t + 1) : (t - 1);

    // xg for this step (plain loads; xgq fixed for the whole launch)
    u64 xv[2][4];
#pragma unroll
    for (int rtl = 0; rtl < 2; ++rtl)
#pragma unroll
      for (int bt = 0; bt < 4; ++bt)
        xv[rtl][bt] = *reinterpret_cast<const u64*>(
            xgq + (((size_t)dir * 64 + sl) * 64 + bt * 16 + lr) * 2048
                + g * 256 + w * 32 + rtl * 16 + lq * 4);

    // wait: all 8 gate-slice blocks of this dir published h(s-1)  [r9 verbatim]
    if (s > 0) {
      while (ald32(&hxfd[lane & 7]) < (unsigned)s) __builtin_amdgcn_s_sleep(8);
    }
    asm volatile("" ::: "memory");           // no load hoisting above the poll
    __syncthreads();

    // stage h(s-1) -> Hlds fragment-contiguous via CACHED loads (fresh addrs)
#pragma unroll
    for (int it = 0; it < 8; ++it) {
      const int sidx = it * 512 + tid;       // 4096 slots of 8 elems
      const int C = sidx >> 4, lrs = sidx & 15;
      const int kts = C >> 4, bts = (C >> 2) & 3, lqs = C & 3;
      const int b = bts * 16 + lrs;
      const int col = kts * 32 + lqs * 8;
      bfrag v;
      if (s == 0) {
        v = *reinterpret_cast<const bfrag*>(h0b + (size_t)b * 512 + col);
      } else if constexpr (LAYER == 0) {
        v = *reinterpret_cast<const bfrag*>(
            y0 + ((size_t)tp * 64 + b) * 1024 + dir * 512 + col);
      } else {
        const float* sf = dout + ((size_t)tp * 64 + b) * 1024 + dir * 512 + col;
        float4 u0 = reinterpret_cast<const float4*>(sf)[0];
        float4 u1 = reinterpret_cast<const float4*>(sf)[1];
        v[0] = (short)f2bf(u0.x); v[1] = (short)f2bf(u0.y);
        v[2] = (short)f2bf(u0.z); v[3] = (short)f2bf(u0.w);
        v[4] = (short)f2bf(u1.x); v[5] = (short)f2bf(u1.y);
        v[6] = (short)f2bf(u1.z); v[7] = (short)f2bf(u1.w);
      }
      *reinterpret_cast<bfrag*>(Hlds + sidx * 8) = v;
    }
    __syncthreads();

    // MFMA: acc = xg + Whh_slice * h(s-1)   (r9 verbatim)
    facc acc[2][4];
#pragma unroll
    for (int rtl = 0; rtl < 2; ++rtl)
#pragma unroll
      for (int bt = 0; bt < 4; ++bt) {
        acc[rtl][bt][0] = bf2f((unsigned short)(xv[rtl][bt] & 0xffff));
        acc[rtl][bt][1] = bf2f((unsigned short)((xv[rtl][bt] >> 16) & 0xffff));
        acc[rtl][bt][2] = bf2f((unsigned short)((xv[rtl][bt] >> 32) & 0xffff));
        acc[rtl][bt][3] = bf2f((unsigned short)((xv[rtl][bt] >> 48) & 0xffff));
      }
    asm volatile("s_nop 3"
                 : "+v"(acc[0][0]), "+v"(acc[0][1]), "+v"(acc[0][2]), "+v"(acc[0][3]),
                   "+v"(acc[1][0]), "+v"(acc[1][1]), "+v"(acc[1][2]), "+v"(acc[1][3]));
#pragma unroll
    for (int kt = 0; kt < 16; ++kt) {
      bfrag Bv[4];
#pragma unroll
      for (int bt = 0; bt < 4; ++bt)
        Bv[bt] = *reinterpret_cast<const bfrag*>(
            Hlds + (((kt * 4 + bt) * 4 + lq) * 16 + lr) * 8);
#pragma unroll
      for (int rtl = 0; rtl < 2; ++rtl)
#pragma unroll
        for (int bt = 0; bt < 4; ++bt)
          acc[rtl][bt] = mfma_bf16(Wreg[rtl * 16 + kt], Bv[bt], acc[rtl][bt]);
    }
    asm volatile("s_nop 7\n\ts_nop 7"
                 : "+v"(acc[0][0]), "+v"(acc[0][1]), "+v"(acc[0][2]), "+v"(acc[0][3]),
                   "+v"(acc[1][0]), "+v"(acc[1][1]), "+v"(acc[1][2]), "+v"(acc[1][3]));

    // gates, state -> swizzled hout (LDS); hn/cn direct at s=1023
#pragma unroll
    for (int rtl = 0; rtl < 2; ++rtl)
#pragma unroll
      for (int bt = 0; bt < 4; ++bt) {
        float ig = sigm(acc[rtl][bt][0]);
        float fg = sigm(acc[rtl][bt][1]);
        float gv = tanhf_(acc[rtl][bt][2]);
        float og = sigm(acc[rtl][bt][3]);
        cst[rtl][bt] = fg * cst[rtl][bt] + ig * gv;
        const float h2 = og * tanhf_(cst[rtl][bt]);
        const int b = bt * 16 + lr;
        const int cl = w * 8 + rtl * 4 + lq;           // 0..63 within slice
        if constexpr (LAYER == 0) hout16[b * 64 + (cl ^ ((b & 7) << 3))] = f2bf(h2);
        else                      hout32[b * 64 + (cl ^ ((b & 7) << 3))] = h2;
        if (s == 1023) {
          const size_t oh = ((size_t)LAYER * 64 + b) * 1024 + dir * 512 + g * 64 + cl;
          dout[67108864 + oh] = h2;
          dout[67239936 + oh] = cst[rtl][bt];
        }
      }
    __syncthreads();

    // repack hout -> global: coalesced 16B (2 x u64 sc1) stores
    if constexpr (LAYER == 0) {
      const int b = tid >> 3, j = tid & 7;             // 512 x 16B chunks
      const unsigned short* sp = hout16 + b * 64 + ((j ^ (b & 7)) << 3);
      u64 d0 = *reinterpret_cast<const u64*>(sp);
      u64 d1 = *reinterpret_cast<const u64*>(sp + 4);
      u64* dp = reinterpret_cast<u64*>(
          y0 + ((size_t)t * 64 + b) * 1024 + dir * 512 + g * 64 + j * 8);
      ast(dp, d0); ast(dp + 1, d1);
    } else {
#pragma unroll
      for (int u = 0; u < 2; ++u) {                    // 1024 x 16B chunks
        const int idx = u * 512 + tid;
        const int b = idx >> 4, j = idx & 15;
        const float* sp = hout32 + b * 64 + ((j ^ ((b & 7) << 1)) << 2);
        u64 d0 = *reinterpret_cast<const u64*>(sp);
        u64 d1 = *reinterpret_cast<const u64*>(sp + 2);
        u64* dp = reinterpret_cast<u64*>(
            dout + ((size_t)t * 64 + b) * 1024 + dir * 512 + g * 64 + j * 4);
        ast(dp, d0); ast(dp + 1, d1);
      }
    }
    __syncthreads();                                   // drains all sc1 stores
    if (tid == 0) ast32(&hxfd[g], (unsigned)(s + 1));  // r9 verbatim
  }

  // persist c-state for the next phase launch (r9)
#pragma unroll
  for (int rtl = 0; rtl < 2; ++rtl)
#pragma unroll
    for (int bt = 0; bt < 4; ++bt)
      cbuf[((size_t)slot * 64 + bt * 16 + lr) * 512
           + g * 64 + w * 8 + rtl * 4 + lq] = cst[rtl][bt];
}

// -------------------------------------------------------------- launch ----
extern "C" void kernel_launch(void* const* d_in, const int* in_sizes, int n_in,
                              void* d_out, int out_size, void* d_ws, size_t ws_size,
                              hipStream_t stream) {
  (void)in_sizes; (void)n_in; (void)out_size; (void)ws_size;
  const float* x  = (const float*)d_in[0];
  const float* h0 = (const float*)d_in[1];
  const float* c0 = (const float*)d_in[2];
  const float* W[12];
  for (int i = 0; i < 12; ++i) W[i] = (const float*)d_in[3 + i];
  // W: Wih0f,Whh0f,b0f, Wih0b,Whh0b,b0b, Wih1f,Whh1f,b1f, Wih1b,Whh1b,b1b

  // ws layout (bytes), total ~245 MB
  char* ws = (char*)d_ws;
  unsigned short* xb   = (unsigned short*)(ws + 0ull);           //  64 MB
  unsigned short* y0   = (unsigned short*)(ws + 67108864ull);    // 128 MB
  unsigned short* xgq  = (unsigned short*)(ws + 201326592ull);   //  32 MB
  unsigned short* PW0F = (unsigned short*)(ws + 234881024ull);   //   4 MB
  unsigned short* PW0B = (unsigned short*)(ws + 239075328ull);   //   4 MB
  unsigned short* PW1F = (unsigned short*)(ws + 243269632ull);   //   6 MB
  unsigned short* PW1B = (unsigned short*)(ws + 249561088ull);   //   6 MB
  float*          PB   = (float*)(ws + 255852544ull);            //  32 KB [4][2048]
  unsigned short* h0b  = (unsigned short*)(ws + 255885312ull);   //  64 KB
  float*          cbuf = (float*)(ws + 255950848ull);            // 512 KB
  unsigned*       hxf  = (unsigned*)(ws + 256475136ull);         // 512 B
  float* dout = (float*)d_out;

  k_cvt_x<<<32768, 256, 0, stream>>>(x, xb);
  k_init<<<128, 256, 0, stream>>>(h0, c0, h0b, cbuf, hxf);
  k_pack<512> <<<8192, 256, 0, stream>>>(W[0], W[1],  W[2],  PW0F, PB + 0);
  k_pack<512> <<<8192, 256, 0, stream>>>(W[3], W[4],  W[5],  PW0B, PB + 2048);
  k_pack<1024><<<12288, 256, 0, stream>>>(W[6], W[7],  W[8],  PW1F, PB + 4096);
  k_pack<1024><<<12288, 256, 0, stream>>>(W[9], W[10], W[11], PW1B, PB + 6144);

  (void)hipFuncSetAttribute((const void*)(&k_scan<0>),
                            hipFuncAttributeMaxDynamicSharedMemorySize, 81920);
  (void)hipFuncSetAttribute((const void*)(&k_scan<1>),
                            hipFuncAttributeMaxDynamicSharedMemorySize, 81920);

  unsigned short *xgqp = xgq, *y0p = y0, *h0bp = h0b;
  float *cbufp = cbuf;
  unsigned* hxfp = hxf;
  const unsigned short *pw0f = PW0F, *pw0b = PW0B, *pw1f = PW1F, *pw1b = PW1B;
  float* doutp = dout;

  for (int ph = 0; ph < 16; ++ph) {
    k_xg<0><<<256, 256, 0, stream>>>(ph, xb, xgq, PW0F, PW0B, PB + 0, PB + 2048);
    int phv = ph;
    void* as[] = {(void*)&phv, (void*)&xgqp, (void*)&y0p, (void*)&doutp,
                  (void*)&h0bp, (void*)&cbufp, (void*)&pw0f, (void*)&pw0b,
                  (void*)&hxfp};
    (void)hipLaunchCooperativeKernel((const void*)(&k_scan<0>), dim3(16), dim3(512),
                                     as, 81920, stream);
  }
  for (int ph = 0; ph < 16; ++ph) {
    k_xg<1><<<256, 256, 0, stream>>>(ph, y0, xgq, PW1F, PW1B, PB + 4096, PB + 6144);
    int phv = ph;
    void* as[] = {(void*)&phv, (void*)&xgqp, (void*)&y0p, (void*)&doutp,
                  (void*)&h0bp, (void*)&cbufp, (void*)&pw1f, (void*)&pw1b,
                  (void*)&hxfp};
    (void)hipLaunchCooperativeKernel((const void*)(&k_scan<1>), dim3(16), dim3(512),
                                     as, 81920, stream);
  }
}